// Round 1
// 754.411 us; speedup vs baseline: 1.1769x; 1.1769x over previous
//
#include <hip/hip_runtime.h>

#define NQ 2048
#define NKK 2048
#define DD 1024
#define HH 16

typedef __attribute__((ext_vector_type(8))) short bf16x8;
typedef __attribute__((ext_vector_type(4))) float f32x4;

__device__ __forceinline__ short f2bf(float f){
    union { float f; unsigned u; } v; v.f = f;
    unsigned u = v.u + 0x7FFFu + ((v.u >> 16) & 1u);
    return (short)(u >> 16);
}
__device__ __forceinline__ float bf2f(unsigned short u){
    union { unsigned u; float f; } v; v.u = ((unsigned)u) << 16;
    return v.f;
}

// async global->LDS, 16B per lane, LDS dest = wave-uniform base + lane*16
__device__ __forceinline__ void gload16(const void* g, void* l){
    __builtin_amdgcn_global_load_lds(
        (__attribute__((address_space(1))) void*)g,
        (__attribute__((address_space(3))) void*)l,
        16, 0, 0);
}

// ---------------- fp32 -> bf16 conversion ----------------
__global__ __launch_bounds__(256) void cvt_bf16(const float* __restrict__ src,
                                                short* __restrict__ dst, int n){
    int i = (blockIdx.x * 256 + threadIdx.x) * 4;
    if (i < n){
        float4 v = *(const float4*)(src + i);
        union { short s[4]; uint2 u; } o;
        o.s[0] = f2bf(v.x); o.s[1] = f2bf(v.y);
        o.s[2] = f2bf(v.z); o.s[3] = f2bf(v.w);
        *(uint2*)(dst + i) = o.u;
    }
}

// ---------------- XPos RoPE (elementwise, pairs) ----------------
__global__ __launch_bounds__(256) void rope_kernel(const short* __restrict__ x,
                                                   short* __restrict__ y,
                                                   const float* __restrict__ fr,
                                                   int N, float scale_base,
                                                   float sign, float prescale){
    int p = blockIdx.x * 256 + threadIdx.x;          // pair index
    int col2 = p & 511;                              // 512 pairs per row of D
    int row  = p >> 9;                               // b*N + n
    int n    = row & (N - 1);
    int i    = col2 & 31;                            // freq index within head
    float t  = (float)n;
    float fv = t * fr[i];
    float c = cosf(fv), s = sinf(fv);
    float power = (t - (float)(N / 2)) / scale_base;
    float sv = ((float)(2 * i) + 0.4f * 64.f) / (1.4f * 64.f);
    float scale = exp2f(sign * power * log2f(sv)) * prescale;
    unsigned xv = *(const unsigned*)(x + 2 * (size_t)p);
    float x0 = bf2f((unsigned short)(xv & 0xFFFFu));
    float x1 = bf2f((unsigned short)(xv >> 16));
    float y0 = (x0 * c - x1 * s) * scale;
    float y1 = (x1 * c + x0 * s) * scale;
    unsigned o = (unsigned)(unsigned short)f2bf(y0) |
                 ((unsigned)(unsigned short)f2bf(y1) << 16);
    *(unsigned*)(y + 2 * (size_t)p) = o;
}

// ---------------- GEMM: C(MxN) = A(MxK) * W(NxK)^T + bias ----------------
// 128x128 tile, 4 waves (2x2), BK=64, global_load_lds staging, 2-phase dbuf.
template<bool F32OUT>
__global__ __launch_bounds__(256) void gemm_bt(const short* __restrict__ A,
                                               const short* __restrict__ W,
                                               const float* __restrict__ bias,
                                               void* __restrict__ Cout,
                                               int M, int N, int K){
    __shared__ __align__(16) short lA[2][128 * 64];
    __shared__ __align__(16) short lB[2][128 * 64];
    int tid = threadIdx.x;
    int wave = tid >> 6, lane = tid & 63;
    int l16 = lane & 15, quad = lane >> 4;
    int wr = wave >> 1, wc = wave & 1;
    int row0 = blockIdx.y * 128, col0 = blockIdx.x * 128;

    // per-lane global source: 8 rows / instr, lane -> (row=lane>>3, col=(lane&7)*8)
    const short* Ab = A + (size_t)(row0 + wave * 32 + (lane >> 3)) * K + (lane & 7) * 8;
    const short* Wb = W + (size_t)(col0 + wave * 32 + (lane >> 3)) * K + (lane & 7) * 8;

    f32x4 acc[4][4];
#pragma unroll
    for (int a = 0; a < 4; a++)
#pragma unroll
        for (int b = 0; b < 4; b++) acc[a][b] = (f32x4){0.f, 0.f, 0.f, 0.f};

    int nt = K >> 6;
    // prologue: stage tile 0
#pragma unroll
    for (int i = 0; i < 4; i++){
        gload16(Ab + (size_t)i * 8 * K, &lA[0][(wave * 32 + i * 8) * 64]);
        gload16(Wb + (size_t)i * 8 * K, &lB[0][(wave * 32 + i * 8) * 64]);
    }
    __syncthreads();

    for (int t = 0; t < nt; t++){
        int cur = t & 1;
        if (t + 1 < nt){
            int k0 = (t + 1) << 6;
#pragma unroll
            for (int i = 0; i < 4; i++){
                gload16(Ab + (size_t)i * 8 * K + k0, &lA[cur ^ 1][(wave * 32 + i * 8) * 64]);
                gload16(Wb + (size_t)i * 8 * K + k0, &lB[cur ^ 1][(wave * 32 + i * 8) * 64]);
            }
        }
#pragma unroll
        for (int kk = 0; kk < 2; kk++){
            bf16x8 af[4], bfr[4];
#pragma unroll
            for (int t4 = 0; t4 < 4; t4++){
                af[t4]  = *(const bf16x8*)&lA[cur][(wr * 64 + t4 * 16 + l16) * 64 + kk * 32 + quad * 8];
                bfr[t4] = *(const bf16x8*)&lB[cur][(wc * 64 + t4 * 16 + l16) * 64 + kk * 32 + quad * 8];
            }
#pragma unroll
            for (int tm = 0; tm < 4; tm++)
#pragma unroll
                for (int tn = 0; tn < 4; tn++)
                    acc[tm][tn] = __builtin_amdgcn_mfma_f32_16x16x32_bf16(af[tm], bfr[tn], acc[tm][tn], 0, 0, 0);
        }
        __syncthreads();   // drains prefetch (vmcnt 0) + read-done for buf swap
    }

#pragma unroll
    for (int tm = 0; tm < 4; tm++){
        int gr = row0 + wr * 64 + tm * 16 + quad * 4;
#pragma unroll
        for (int tn = 0; tn < 4; tn++){
            int gc = col0 + wc * 64 + tn * 16 + l16;
            float bv = bias[gc];
#pragma unroll
            for (int r = 0; r < 4; r++){
                float v = acc[tm][tn][r] + bv;
                if (F32OUT) ((float*)Cout)[(size_t)(gr + r) * N + gc] = v;
                else        ((short*)Cout)[(size_t)(gr + r) * N + gc] = f2bf(v);
            }
        }
    }
}

// ---------------- transpose V: (b,n,D) -> vT (b,h,hd,k) ------------------
// LDS-tiled 64x64, both global sides fully coalesced (uint4).
__global__ __launch_bounds__(256) void transpose_v(const short* __restrict__ vp,
                                                   short* __restrict__ vT){
    __shared__ __align__(16) short tl[64 * 66];
    int kt = blockIdx.x;      // 32 k-tiles
    int bh = blockIdx.y;      // b*H+h
    int b = bh >> 4, h = bh & 15;
    int tid = threadIdx.x;
    const short* src = vp + ((size_t)(b * NKK + kt * 64)) * DD + h * 64;
#pragma unroll
    for (int rd = 0; rd < 2; rd++){
        int kl = (tid >> 3) + rd * 32, c8 = (tid & 7) * 8;
        *(uint4*)&tl[kl * 66 + c8] = *(const uint4*)(src + (size_t)kl * DD + c8);
    }
    __syncthreads();
    short* dst = vT + ((size_t)(bh * 64)) * NKK + kt * 64;
#pragma unroll
    for (int rd = 0; rd < 2; rd++){
        int hd = (tid >> 3) + rd * 32, k8 = (tid & 7) * 8;
        union { short s[8]; uint4 u; } o;
#pragma unroll
        for (int j = 0; j < 8; j++) o.s[j] = tl[(k8 + j) * 66 + hd];
        *(uint4*)(dst + (size_t)hd * NKK + k8) = o.u;
    }
}

// ---------------- fused attention (two-pass flash, attn materialized) ----
__global__ __launch_bounds__(256, 4) void attn_kernel(const short* __restrict__ qp,
                                                      const short* __restrict__ kp,
                                                      const short* __restrict__ vT,
                                                      float* __restrict__ attn,
                                                      short* __restrict__ op){
    __shared__ __align__(16) short lK[64 * 64];
    __shared__ __align__(16) short lV[64 * 64];   // [hd][k]
    __shared__ __align__(16) float lPf[64 * 68];  // [q][k] fp32, padded (bank-safe)
    __shared__ float lMf[64], lLi[64];

    int qt = blockIdx.x;      // q tile (64 rows)
    int bh = blockIdx.y;
    int b = bh >> 4, h = bh & 15;
    int tid = threadIdx.x, wave = tid >> 6, lane = tid & 63;
    int l16 = lane & 15, quad = lane >> 4;

    int q0 = qt * 64;
    int qrow = q0 + wave * 16 + l16;
    const short* qb = qp + ((size_t)(b * NQ + qrow)) * DD + h * 64;
    bf16x8 qf[2];
    qf[0] = *(const bf16x8*)(qb + quad * 8);
    qf[1] = *(const bf16x8*)(qb + 32 + quad * 8);

    const short* kb = kp + ((size_t)(b * NKK)) * DD + h * 64;
    const short* vb = vT + ((size_t)(bh * 64)) * NKK;

    // -------- pass A: S^T = K*Q^T, online max/sum fully in-lane --------
    float m = -1e30f, l = 0.f;
    for (int kt = 0; kt < 32; kt++){
#pragma unroll
        for (int i = 0; i < 2; i++)
            gload16(kb + (size_t)(kt * 64 + wave * 16 + i * 8 + (lane >> 3)) * DD + (lane & 7) * 8,
                    &lK[(wave * 16 + i * 8) * 64]);
        __syncthreads();
        f32x4 St[4];
#pragma unroll
        for (int t = 0; t < 4; t++){
            f32x4 a = (f32x4){0.f, 0.f, 0.f, 0.f};
#pragma unroll
            for (int kk = 0; kk < 2; kk++){
                bf16x8 kf = *(const bf16x8*)&lK[(t * 16 + l16) * 64 + kk * 32 + quad * 8];
                a = __builtin_amdgcn_mfma_f32_16x16x32_bf16(kf, qf[kk], a, 0, 0, 0);
            }
            St[t] = a;
        }
        float mx = m;
#pragma unroll
        for (int t = 0; t < 4; t++)
#pragma unroll
            for (int r = 0; r < 4; r++) mx = fmaxf(mx, St[t][r]);
        float sum = 0.f;
#pragma unroll
        for (int t = 0; t < 4; t++)
#pragma unroll
            for (int r = 0; r < 4; r++) sum += __expf(St[t][r] - mx);
        l = l * __expf(m - mx) + sum;
        m = mx;
        __syncthreads();
    }
    // reduce across quads (each lane covered k = {16t + quad*4 + r})
    float M = fmaxf(m, __shfl_xor(m, 16, 64));
    M = fmaxf(M, __shfl_xor(M, 32, 64));
    float ls = l * __expf(m - M);
    ls += __shfl_xor(ls, 16, 64);
    ls += __shfl_xor(ls, 32, 64);
    if (quad == 0){ lMf[wave * 16 + l16] = M; lLi[wave * 16 + l16] = 1.f / ls; }
    __syncthreads();
    float mf[4], il[4];
#pragma unroll
    for (int r = 0; r < 4; r++){
        mf[r] = lMf[wave * 16 + quad * 4 + r];
        il[r] = lLi[wave * 16 + quad * 4 + r];
    }

    // -------- pass B: S normal orientation, write attn, O += P*V --------
    f32x4 O[4];
#pragma unroll
    for (int th = 0; th < 4; th++) O[th] = (f32x4){0.f, 0.f, 0.f, 0.f};
    float* ab = attn + (((size_t)bh * NQ) + q0 + wave * 16) * NKK;

    for (int kt = 0; kt < 32; kt++){
#pragma unroll
        for (int i = 0; i < 2; i++){
            gload16(kb + (size_t)(kt * 64 + wave * 16 + i * 8 + (lane >> 3)) * DD + (lane & 7) * 8,
                    &lK[(wave * 16 + i * 8) * 64]);
            gload16(vb + (size_t)(wave * 16 + i * 8 + (lane >> 3)) * NKK + kt * 64 + (lane & 7) * 8,
                    &lV[(wave * 16 + i * 8) * 64]);
        }
        __syncthreads();
        f32x4 S[4];
#pragma unroll
        for (int tn = 0; tn < 4; tn++){
            f32x4 a = (f32x4){0.f, 0.f, 0.f, 0.f};
#pragma unroll
            for (int kk = 0; kk < 2; kk++){
                bf16x8 kf = *(const bf16x8*)&lK[(tn * 16 + l16) * 64 + kk * 32 + quad * 8];
                a = __builtin_amdgcn_mfma_f32_16x16x32_bf16(qf[kk], kf, a, 0, 0, 0);
            }
            S[tn] = a;
        }
        // P (fp32) into wave-private LDS strip; lgkmcnt orders ds ops, no barrier
#pragma unroll
        for (int tn = 0; tn < 4; tn++)
#pragma unroll
            for (int r = 0; r < 4; r++)
                lPf[(wave * 16 + quad * 4 + r) * 68 + tn * 16 + l16] =
                    __expf(S[tn][r] - mf[r]) * il[r];
        // coalesced nontemporal float4 attn store (256B contiguous per quad)
#pragma unroll
        for (int j = 0; j < 4; j++){
            f32x4 pv = *(const f32x4*)&lPf[(wave * 16 + j * 4 + quad) * 68 + l16 * 4];
            __builtin_nontemporal_store(pv,
                (f32x4*)&ab[(size_t)(j * 4 + quad) * NKK + kt * 64 + l16 * 4]);
        }
        // PV: rebuild bf16 P fragment from the same fp32 strip
#pragma unroll
        for (int kk = 0; kk < 2; kk++){
            f32x4 p0 = *(const f32x4*)&lPf[(wave * 16 + l16) * 68 + kk * 32 + quad * 8];
            f32x4 p1 = *(const f32x4*)&lPf[(wave * 16 + l16) * 68 + kk * 32 + quad * 8 + 4];
            union { short s[8]; bf16x8 v; } pf;
#pragma unroll
            for (int r = 0; r < 4; r++){ pf.s[r] = f2bf(p0[r]); pf.s[4 + r] = f2bf(p1[r]); }
#pragma unroll
            for (int th = 0; th < 4; th++){
                bf16x8 vf = *(const bf16x8*)&lV[(th * 16 + l16) * 64 + kk * 32 + quad * 8];
                O[th] = __builtin_amdgcn_mfma_f32_16x16x32_bf16(pf.v, vf, O[th], 0, 0, 0);
            }
        }
        __syncthreads();
    }
    // epilogue: O -> op (b, q, h*64+hd) bf16
#pragma unroll
    for (int th = 0; th < 4; th++){
#pragma unroll
        for (int r = 0; r < 4; r++){
            int q = q0 + wave * 16 + quad * 4 + r;
            op[((size_t)(b * NQ + q)) * DD + h * 64 + th * 16 + l16] = f2bf(O[th][r]);
        }
    }
}

extern "C" void kernel_launch(void* const* d_in, const int* in_sizes, int n_in,
                              void* d_out, int out_size, void* d_ws, size_t ws_size,
                              hipStream_t stream) {
    const float* q_seq = (const float*)d_in[0];
    const float* kv_seq = (const float*)d_in[1];
    const float* Wq = (const float*)d_in[2];
    const float* bq = (const float*)d_in[3];
    const float* Wk = (const float*)d_in[4];
    const float* bk = (const float*)d_in[5];
    const float* Wv = (const float*)d_in[6];
    const float* bv = (const float*)d_in[7];
    const float* Wo = (const float*)d_in[8];
    const float* bo = (const float*)d_in[9];
    const float* freqs_q = (const float*)d_in[10];
    const float* freqs_kv = (const float*)d_in[11];

    float* out0 = (float*)d_out;                     // (B, NQ, D)
    float* attn = (float*)d_out + 4194304;           // (B, H, NQ, NK)

    // workspace layout (bf16 shorts)
    short* qb  = (short*)d_ws;          // 4194304  q_seq bf16
    short* kvb = qb  + 4194304;         // 4194304  kv_seq bf16
    short* wqb = kvb + 4194304;         // 1048576
    short* wkb = wqb + 1048576;
    short* wvb = wkb + 1048576;
    short* wob = wvb + 1048576;
    short* tmp = wob + 1048576;         // 4194304  pre-rope proj / O
    short* qpb = tmp + 4194304;         // 4194304  q post-rope
    short* kpb = qpb + 4194304;         // 4194304  k post-rope
    short* vpb = kpb + 4194304;         // 4194304  v
    short* vTb = qb;                    // alias: q_seq bf16 dead after GEMM_Q
    short* opb = tmp;                   // alias: tmp dead after rope_k

    // 1) conversions
    cvt_bf16<<<4096, 256, 0, stream>>>(q_seq, qb, 4194304);
    cvt_bf16<<<4096, 256, 0, stream>>>(kv_seq, kvb, 4194304);
    cvt_bf16<<<1024, 256, 0, stream>>>(Wq, wqb, 1048576);
    cvt_bf16<<<1024, 256, 0, stream>>>(Wk, wkb, 1048576);
    cvt_bf16<<<1024, 256, 0, stream>>>(Wv, wvb, 1048576);
    cvt_bf16<<<1024, 256, 0, stream>>>(Wo, wob, 1048576);

    dim3 ggrid(8, 32);   // N/128, M/128
    // 2) Q proj -> rope(+fold 1/sqrt(HD)=0.125)
    gemm_bt<false><<<ggrid, 256, 0, stream>>>(qb, wqb, bq, tmp, 4096, 1024, 1024);
    rope_kernel<<<8192, 256, 0, stream>>>(tmp, qpb, freqs_q, NQ, 4096.f, 1.f, 0.125f);
    // 3) K proj -> rope (sign -1)
    gemm_bt<false><<<ggrid, 256, 0, stream>>>(kvb, wkb, bk, tmp, 4096, 1024, 1024);
    rope_kernel<<<8192, 256, 0, stream>>>(tmp, kpb, freqs_kv, NKK, 4096.f, -1.f, 1.f);
    // 4) V proj, transpose
    gemm_bt<false><<<ggrid, 256, 0, stream>>>(kvb, wvb, bv, vpb, 4096, 1024, 1024);
    transpose_v<<<dim3(32, 32), 256, 0, stream>>>(vpb, vTb);
    // 5) attention
    attn_kernel<<<dim3(32, 32), 256, 0, stream>>>(qpb, kpb, vTb, attn, opb);
    // 6) out projection (fp32 out)
    gemm_bt<true><<<ggrid, 256, 0, stream>>>(opb, wob, bo, out0, 4096, 1024, 1024);
}

// Round 2
// 719.007 us; speedup vs baseline: 1.2348x; 1.0492x over previous
//
#include <hip/hip_runtime.h>

#define NQ 2048
#define NKK 2048
#define DD 1024
#define HH 16

typedef __attribute__((ext_vector_type(8))) short bf16x8;
typedef __attribute__((ext_vector_type(4))) float f32x4;

__device__ __forceinline__ short f2bf(float f){
    union { float f; unsigned u; } v; v.f = f;
    unsigned u = v.u + 0x7FFFu + ((v.u >> 16) & 1u);
    return (short)(u >> 16);
}
__device__ __forceinline__ float bf2f(unsigned short u){
    union { unsigned u; float f; } v; v.u = ((unsigned)u) << 16;
    return v.f;
}

// async global->LDS, 16B per lane, LDS dest = wave-uniform base + lane*16
__device__ __forceinline__ void gload16(const void* g, void* l){
    __builtin_amdgcn_global_load_lds(
        (__attribute__((address_space(1))) void*)g,
        (__attribute__((address_space(3))) void*)l,
        16, 0, 0);
}

// ---------------- fused fp32 -> bf16 conversion (all 6 tensors) ----------
__global__ __launch_bounds__(256) void cvt_all(
    const float* __restrict__ q, const float* __restrict__ kv,
    const float* __restrict__ wq, const float* __restrict__ wk,
    const float* __restrict__ wv, const float* __restrict__ wo,
    short* __restrict__ qb, short* __restrict__ kvb,
    short* __restrict__ wqb, short* __restrict__ wkb,
    short* __restrict__ wvb, short* __restrict__ wob){
    int b = blockIdx.x;
    const float* src; short* dst; int off;
    if      (b < 4096) { src = q;  dst = qb;  off = b; }
    else if (b < 8192) { src = kv; dst = kvb; off = b - 4096; }
    else if (b < 9216) { src = wq; dst = wqb; off = b - 8192; }
    else if (b < 10240){ src = wk; dst = wkb; off = b - 9216; }
    else if (b < 11264){ src = wv; dst = wvb; off = b - 10240; }
    else               { src = wo; dst = wob; off = b - 11264; }
    int i = (off * 256 + threadIdx.x) * 4;
    float4 v = *(const float4*)(src + i);
    union { short s[4]; uint2 u; } o;
    o.s[0] = f2bf(v.x); o.s[1] = f2bf(v.y);
    o.s[2] = f2bf(v.z); o.s[3] = f2bf(v.w);
    *(uint2*)(dst + i) = o.u;
}

// ---------------- XPos rope tables: (cos*scale, sin*scale) per (n,i) -----
// tq: sign=+1, prescale 0.125 (folds 1/sqrt(HD)); tk: sign=-1, prescale 1.
__global__ __launch_bounds__(256) void rope_tables(
    const float* __restrict__ frq, const float* __restrict__ frk,
    float2* __restrict__ tq, float2* __restrict__ tk){
    int idx = blockIdx.x * 256 + threadIdx.x;      // 65536 = 2048 * 32
    int n = idx >> 5, i = idx & 31;
    float t = (float)n;
    float power = (t - 1024.f) / 4096.f;
    float sv = ((float)(2 * i) + 0.4f * 64.f) / (1.4f * 64.f);
    float lg = log2f(sv);
    float scq = exp2f(power * lg) * 0.125f;
    float sck = exp2f(-power * lg);
    float fq = t * frq[i], fk = t * frk[i];
    tq[idx] = make_float2(cosf(fq) * scq, sinf(fq) * scq);
    tk[idx] = make_float2(cosf(fk) * sck, sinf(fk) * sck);
}

// ---------------- fused QKV projection ----------------------------------
// grid (24, 32): blockIdx.x>>3 selects sector {0:Q+rope, 1:K+rope, 2:V->vT}.
// 128x128 tile, 4 waves, BK=64, single-buffer gload_lds (all 768 blocks
// co-resident at 3/CU -> cross-block latency hiding, m97 structure).
__global__ __launch_bounds__(256, 3) void proj_fused(
    const short* __restrict__ qb, const short* __restrict__ kvb,
    const short* __restrict__ wqb, const short* __restrict__ wkb,
    const short* __restrict__ wvb,
    const float* __restrict__ bq, const float* __restrict__ bk,
    const float* __restrict__ bv,
    const float2* __restrict__ tq, const float2* __restrict__ tk,
    short* __restrict__ qpb, short* __restrict__ kpb,
    short* __restrict__ vTb){
    __shared__ __align__(16) short lA[128 * 64];
    __shared__ __align__(16) short lB[128 * 64];
    int bx = blockIdx.x;
    int sec = bx >> 3, bxx = bx & 7;
    const short* A = (sec == 0) ? qb : kvb;
    const short* W = (sec == 0) ? wqb : (sec == 1 ? wkb : wvb);
    const float* bias = (sec == 0) ? bq : (sec == 1 ? bk : bv);
    const int K = 1024;
    int tid = threadIdx.x;
    int wave = tid >> 6, lane = tid & 63;
    int l16 = lane & 15, quad = lane >> 4;
    int wr = wave >> 1, wc = wave & 1;
    int row0 = blockIdx.y * 128, col0 = bxx * 128;

    const short* Ab = A + (size_t)(row0 + wave * 32 + (lane >> 3)) * K + (lane & 7) * 8;
    const short* Wb = W + (size_t)(col0 + wave * 32 + (lane >> 3)) * K + (lane & 7) * 8;

    f32x4 acc[4][4];
#pragma unroll
    for (int a = 0; a < 4; a++)
#pragma unroll
        for (int b = 0; b < 4; b++) acc[a][b] = (f32x4){0.f, 0.f, 0.f, 0.f};

    for (int k0 = 0; k0 < K; k0 += 64){
#pragma unroll
        for (int i = 0; i < 4; i++){
            gload16(Ab + (size_t)i * 8 * K + k0, &lA[(wave * 32 + i * 8) * 64]);
            gload16(Wb + (size_t)i * 8 * K + k0, &lB[(wave * 32 + i * 8) * 64]);
        }
        __syncthreads();
#pragma unroll
        for (int kk = 0; kk < 2; kk++){
            bf16x8 af[4], bfr[4];
#pragma unroll
            for (int t4 = 0; t4 < 4; t4++){
                af[t4]  = *(const bf16x8*)&lA[(wr * 64 + t4 * 16 + l16) * 64 + kk * 32 + quad * 8];
                bfr[t4] = *(const bf16x8*)&lB[(wc * 64 + t4 * 16 + l16) * 64 + kk * 32 + quad * 8];
            }
#pragma unroll
            for (int tm = 0; tm < 4; tm++)
#pragma unroll
                for (int tn = 0; tn < 4; tn++)
                    acc[tm][tn] = __builtin_amdgcn_mfma_f32_16x16x32_bf16(af[tm], bfr[tn], acc[tm][tn], 0, 0, 0);
        }
        __syncthreads();
    }

    if (sec == 2){
        // V: write directly transposed (b,h,hd,k); 4 consecutive k per lane = 8B store
#pragma unroll
        for (int tm = 0; tm < 4; tm++){
            int gr = row0 + wr * 64 + tm * 16 + quad * 4;
            int b = gr >> 11, k = gr & 2047;
#pragma unroll
            for (int tn = 0; tn < 4; tn++){
                int gc = col0 + wc * 64 + tn * 16 + l16;
                int h = gc >> 6, hd = gc & 63;
                float bvv = bias[gc];
                union { short s[4]; uint2 u; } o;
#pragma unroll
                for (int r = 0; r < 4; r++) o.s[r] = f2bf(acc[tm][tn][r] + bvv);
                *(uint2*)&vTb[((size_t)((b * 16 + h) * 64 + hd)) * 2048 + k] = o.u;
            }
        }
    } else {
        // Q/K: fused XPos rope via table + shfl-partner (pairs = adjacent lanes)
        const float2* tbl = sec ? tk : tq;
        short* outp = sec ? kpb : qpb;
#pragma unroll
        for (int tm = 0; tm < 4; tm++){
#pragma unroll
            for (int tn = 0; tn < 4; tn++){
                int gc = col0 + wc * 64 + tn * 16 + l16;
                int fi = (tn * 16 + l16) >> 1;               // freq index in head
                float sgn = (l16 & 1) ? 1.f : -1.f;
                float bvv = bias[gc];
#pragma unroll
                for (int r = 0; r < 4; r++){
                    int gr = row0 + wr * 64 + tm * 16 + quad * 4 + r;
                    int n = gr & 2047;
                    float v = acc[tm][tn][r] + bvv;
                    float vp = __shfl_xor(v, 1, 64);         // rotate-half partner
                    float2 cs = tbl[n * 32 + fi];
                    float y = v * cs.x + sgn * vp * cs.y;
                    outp[(size_t)gr * 1024 + gc] = f2bf(y);
                }
            }
        }
    }
}

// ---------------- GEMM: C(MxN) = A(MxK) * W(NxK)^T + bias (O-proj) ------
template<bool F32OUT>
__global__ __launch_bounds__(256) void gemm_bt(const short* __restrict__ A,
                                               const short* __restrict__ W,
                                               const float* __restrict__ bias,
                                               void* __restrict__ Cout,
                                               int M, int N, int K){
    __shared__ __align__(16) short lA[2][128 * 64];
    __shared__ __align__(16) short lB[2][128 * 64];
    int tid = threadIdx.x;
    int wave = tid >> 6, lane = tid & 63;
    int l16 = lane & 15, quad = lane >> 4;
    int wr = wave >> 1, wc = wave & 1;
    int row0 = blockIdx.y * 128, col0 = blockIdx.x * 128;

    const short* Ab = A + (size_t)(row0 + wave * 32 + (lane >> 3)) * K + (lane & 7) * 8;
    const short* Wb = W + (size_t)(col0 + wave * 32 + (lane >> 3)) * K + (lane & 7) * 8;

    f32x4 acc[4][4];
#pragma unroll
    for (int a = 0; a < 4; a++)
#pragma unroll
        for (int b = 0; b < 4; b++) acc[a][b] = (f32x4){0.f, 0.f, 0.f, 0.f};

    int nt = K >> 6;
#pragma unroll
    for (int i = 0; i < 4; i++){
        gload16(Ab + (size_t)i * 8 * K, &lA[0][(wave * 32 + i * 8) * 64]);
        gload16(Wb + (size_t)i * 8 * K, &lB[0][(wave * 32 + i * 8) * 64]);
    }
    __syncthreads();

    for (int t = 0; t < nt; t++){
        int cur = t & 1;
        if (t + 1 < nt){
            int k0 = (t + 1) << 6;
#pragma unroll
            for (int i = 0; i < 4; i++){
                gload16(Ab + (size_t)i * 8 * K + k0, &lA[cur ^ 1][(wave * 32 + i * 8) * 64]);
                gload16(Wb + (size_t)i * 8 * K + k0, &lB[cur ^ 1][(wave * 32 + i * 8) * 64]);
            }
        }
#pragma unroll
        for (int kk = 0; kk < 2; kk++){
            bf16x8 af[4], bfr[4];
#pragma unroll
            for (int t4 = 0; t4 < 4; t4++){
                af[t4]  = *(const bf16x8*)&lA[cur][(wr * 64 + t4 * 16 + l16) * 64 + kk * 32 + quad * 8];
                bfr[t4] = *(const bf16x8*)&lB[cur][(wc * 64 + t4 * 16 + l16) * 64 + kk * 32 + quad * 8];
            }
#pragma unroll
            for (int tm = 0; tm < 4; tm++)
#pragma unroll
                for (int tn = 0; tn < 4; tn++)
                    acc[tm][tn] = __builtin_amdgcn_mfma_f32_16x16x32_bf16(af[tm], bfr[tn], acc[tm][tn], 0, 0, 0);
        }
        __syncthreads();
    }

#pragma unroll
    for (int tm = 0; tm < 4; tm++){
        int gr = row0 + wr * 64 + tm * 16 + quad * 4;
#pragma unroll
        for (int tn = 0; tn < 4; tn++){
            int gc = col0 + wc * 64 + tn * 16 + l16;
            float bv = bias[gc];
#pragma unroll
            for (int r = 0; r < 4; r++){
                float v = acc[tm][tn][r] + bv;
                if (F32OUT) ((float*)Cout)[(size_t)(gr + r) * N + gc] = v;
                else        ((short*)Cout)[(size_t)(gr + r) * N + gc] = f2bf(v);
            }
        }
    }
}

// ---------------- fused attention (two-pass flash, attn materialized) ----
// Double-buffered K/V staging (T3 minimum 2-phase), XCD-swizzled grid.
__global__ __launch_bounds__(256, 3) void attn_kernel(const short* __restrict__ qp,
                                                      const short* __restrict__ kp,
                                                      const short* __restrict__ vT,
                                                      float* __restrict__ attn,
                                                      short* __restrict__ op){
    __shared__ __align__(16) short lK[2][64 * 64];
    __shared__ __align__(16) short lV[2][64 * 64];   // [hd][k]
    __shared__ __align__(16) float lPf[64 * 68];     // [q][k] fp32, padded
    __shared__ float lMf[64], lLi[64];

    // XCD-aware remap: each XCD owns bh ≡ xcd (mod 8), 4 of them (K+V 2MB, L2-fit)
    int flat = blockIdx.y * 32 + blockIdx.x;   // 0..1023
    int xcd = flat & 7, idx = flat >> 3;
    int qt = idx & 31;
    int bh = xcd + 8 * (idx >> 5);
    int b = bh >> 4, h = bh & 15;
    int tid = threadIdx.x, wave = tid >> 6, lane = tid & 63;
    int l16 = lane & 15, quad = lane >> 4;

    int q0 = qt * 64;
    int qrow = q0 + wave * 16 + l16;
    const short* qb = qp + ((size_t)(b * NQ + qrow)) * DD + h * 64;
    bf16x8 qf[2];
    qf[0] = *(const bf16x8*)(qb + quad * 8);
    qf[1] = *(const bf16x8*)(qb + 32 + quad * 8);

    const short* kb = kp + ((size_t)(b * NKK)) * DD + h * 64;
    const short* vb = vT + ((size_t)(bh * 64)) * NKK;

#define STAGE_K(kt, buf) \
    { _Pragma("unroll") \
      for (int i = 0; i < 2; i++) \
          gload16(kb + (size_t)((kt) * 64 + wave * 16 + i * 8 + (lane >> 3)) * DD + (lane & 7) * 8, \
                  &lK[buf][(wave * 16 + i * 8) * 64]); }
#define STAGE_V(kt, buf) \
    { _Pragma("unroll") \
      for (int i = 0; i < 2; i++) \
          gload16(vb + (size_t)(wave * 16 + i * 8 + (lane >> 3)) * NKK + (kt) * 64 + (lane & 7) * 8, \
                  &lV[buf][(wave * 16 + i * 8) * 64]); }

    // -------- pass A: S^T = K*Q^T, online max/sum fully in-lane --------
    float m = -1e30f, l = 0.f;
    STAGE_K(0, 0);
    __syncthreads();
    for (int kt = 0; kt < 32; kt++){
        int cur = kt & 1;
        if (kt < 31) STAGE_K(kt + 1, cur ^ 1);
        f32x4 St[4];
#pragma unroll
        for (int t = 0; t < 4; t++){
            f32x4 a = (f32x4){0.f, 0.f, 0.f, 0.f};
#pragma unroll
            for (int kk = 0; kk < 2; kk++){
                bf16x8 kf = *(const bf16x8*)&lK[cur][(t * 16 + l16) * 64 + kk * 32 + quad * 8];
                a = __builtin_amdgcn_mfma_f32_16x16x32_bf16(kf, qf[kk], a, 0, 0, 0);
            }
            St[t] = a;
        }
        float mx = m;
#pragma unroll
        for (int t = 0; t < 4; t++)
#pragma unroll
            for (int r = 0; r < 4; r++) mx = fmaxf(mx, St[t][r]);
        float sum = 0.f;
#pragma unroll
        for (int t = 0; t < 4; t++)
#pragma unroll
            for (int r = 0; r < 4; r++) sum += __expf(St[t][r] - mx);
        l = l * __expf(m - mx) + sum;
        m = mx;
        __syncthreads();   // all reads of lK[cur] done; prefetch drained
    }
    // reduce across quads (each lane covered k = {16t + quad*4 + r})
    float M = fmaxf(m, __shfl_xor(m, 16, 64));
    M = fmaxf(M, __shfl_xor(M, 32, 64));
    float ls = l * __expf(m - M);
    ls += __shfl_xor(ls, 16, 64);
    ls += __shfl_xor(ls, 32, 64);
    if (quad == 0){ lMf[wave * 16 + l16] = M; lLi[wave * 16 + l16] = 1.f / ls; }
    __syncthreads();
    float mf[4], il[4];
#pragma unroll
    for (int r = 0; r < 4; r++){
        mf[r] = lMf[wave * 16 + quad * 4 + r];
        il[r] = lLi[wave * 16 + quad * 4 + r];
    }

    // -------- pass B: S normal orientation, write attn, O += P*V --------
    f32x4 O[4];
#pragma unroll
    for (int th = 0; th < 4; th++) O[th] = (f32x4){0.f, 0.f, 0.f, 0.f};
    float* ab = attn + (((size_t)bh * NQ) + q0 + wave * 16) * NKK;

    STAGE_K(0, 0);
    STAGE_V(0, 0);
    __syncthreads();
    for (int kt = 0; kt < 32; kt++){
        int cur = kt & 1;
        if (kt < 31){ STAGE_K(kt + 1, cur ^ 1); STAGE_V(kt + 1, cur ^ 1); }
        f32x4 S[4];
#pragma unroll
        for (int tn = 0; tn < 4; tn++){
            f32x4 a = (f32x4){0.f, 0.f, 0.f, 0.f};
#pragma unroll
            for (int kk = 0; kk < 2; kk++){
                bf16x8 kf = *(const bf16x8*)&lK[cur][(tn * 16 + l16) * 64 + kk * 32 + quad * 8];
                a = __builtin_amdgcn_mfma_f32_16x16x32_bf16(qf[kk], kf, a, 0, 0, 0);
            }
            S[tn] = a;
        }
        // P (fp32) into wave-private LDS strip; same-wave ds ordering only
#pragma unroll
        for (int tn = 0; tn < 4; tn++)
#pragma unroll
            for (int r = 0; r < 4; r++)
                lPf[(wave * 16 + quad * 4 + r) * 68 + tn * 16 + l16] =
                    __expf(S[tn][r] - mf[r]) * il[r];
        // coalesced nontemporal float4 attn store (256B contiguous per quad)
#pragma unroll
        for (int j = 0; j < 4; j++){
            f32x4 pv = *(const f32x4*)&lPf[(wave * 16 + j * 4 + quad) * 68 + l16 * 4];
            __builtin_nontemporal_store(pv,
                (f32x4*)&ab[(size_t)(j * 4 + quad) * NKK + kt * 64 + l16 * 4]);
        }
        // PV: rebuild bf16 P fragment from the same fp32 strip
#pragma unroll
        for (int kk = 0; kk < 2; kk++){
            f32x4 p0 = *(const f32x4*)&lPf[(wave * 16 + l16) * 68 + kk * 32 + quad * 8];
            f32x4 p1 = *(const f32x4*)&lPf[(wave * 16 + l16) * 68 + kk * 32 + quad * 8 + 4];
            union { short s[8]; bf16x8 v; } pf;
#pragma unroll
            for (int r = 0; r < 4; r++){ pf.s[r] = f2bf(p0[r]); pf.s[4 + r] = f2bf(p1[r]); }
#pragma unroll
            for (int th = 0; th < 4; th++){
                bf16x8 vf = *(const bf16x8*)&lV[cur][(th * 16 + l16) * 64 + kk * 32 + quad * 8];
                O[th] = __builtin_amdgcn_mfma_f32_16x16x32_bf16(pf.v, vf, O[th], 0, 0, 0);
            }
        }
        __syncthreads();
    }
    // epilogue: O -> op (b, q, h*64+hd) bf16
#pragma unroll
    for (int th = 0; th < 4; th++){
#pragma unroll
        for (int r = 0; r < 4; r++){
            int q = q0 + wave * 16 + quad * 4 + r;
            op[((size_t)(b * NQ + q)) * DD + h * 64 + th * 16 + l16] = f2bf(O[th][r]);
        }
    }
#undef STAGE_K
#undef STAGE_V
}

extern "C" void kernel_launch(void* const* d_in, const int* in_sizes, int n_in,
                              void* d_out, int out_size, void* d_ws, size_t ws_size,
                              hipStream_t stream) {
    const float* q_seq = (const float*)d_in[0];
    const float* kv_seq = (const float*)d_in[1];
    const float* Wq = (const float*)d_in[2];
    const float* bq = (const float*)d_in[3];
    const float* Wk = (const float*)d_in[4];
    const float* bk = (const float*)d_in[5];
    const float* Wv = (const float*)d_in[6];
    const float* bv = (const float*)d_in[7];
    const float* Wo = (const float*)d_in[8];
    const float* bo = (const float*)d_in[9];
    const float* freqs_q = (const float*)d_in[10];
    const float* freqs_kv = (const float*)d_in[11];

    float* out0 = (float*)d_out;                     // (B, NQ, D)
    float* attn = (float*)d_out + 4194304;           // (B, H, NQ, NK)

    // workspace layout (bf16 shorts)
    short* qb  = (short*)d_ws;          // 4194304
    short* kvb = qb  + 4194304;         // 4194304
    short* wqb = kvb + 4194304;         // 1048576
    short* wkb = wqb + 1048576;
    short* wvb = wkb + 1048576;
    short* wob = wvb + 1048576;
    short* qpb = wob + 1048576;         // 4194304  q post-rope
    short* kpb = qpb + 4194304;         // 4194304  k post-rope
    short* vTb = kpb + 4194304;         // 4194304  v transposed
    float2* tq = (float2*)(vTb + 4194304);  // 65536 float2 (512 KB)
    float2* tk = tq + 65536;                // 65536 float2
    short* opb = qb;                    // alias: qb dead after proj_fused

    // 1) conversions (one launch)
    cvt_all<<<12288, 256, 0, stream>>>(q_seq, kv_seq, Wq, Wk, Wv, Wo,
                                       qb, kvb, wqb, wkb, wvb, wob);
    // 2) rope tables
    rope_tables<<<256, 256, 0, stream>>>(freqs_q, freqs_kv, tq, tk);
    // 3) fused Q/K/V projection (+rope epilogue, +transposed V write)
    proj_fused<<<dim3(24, 32), 256, 0, stream>>>(qb, kvb, wqb, wkb, wvb,
                                                 bq, bk, bv, tq, tk,
                                                 qpb, kpb, vTb);
    // 4) attention
    attn_kernel<<<dim3(32, 32), 256, 0, stream>>>(qpb, kpb, vTb, attn, opb);
    // 5) out projection (fp32 out)
    gemm_bt<true><<<dim3(8, 32), 256, 0, stream>>>(opb, wob, bo, out0, 4096, 1024, 1024);
}